// Round 8
// baseline (270.780 us; speedup 1.0000x reference)
//
#include <hip/hip_runtime.h>
#include <hip/hip_bf16.h>
#include <math.h>

#define S 2048
#define D 2048
#define NQ 32
#define NKV 8
#define HD 64
#define HALF 32
#define NREP 4
#define QKV_N 3072           // NQ*HD + 2*NKV*HD
#define KCOL 2048            // K starts here in fused QKV buffer
#define VCOL 2560            // V starts here

typedef unsigned short ushort_t;
typedef __attribute__((ext_vector_type(8))) short bf16x8;   // 8 bf16 = 4 VGPRs
typedef __attribute__((ext_vector_type(4))) float f32x4;
typedef __attribute__((ext_vector_type(4))) unsigned short us4;
typedef float f4 __attribute__((ext_vector_type(4)));

__device__ __forceinline__ ushort_t f2bf(float f) {
    __hip_bfloat16 h = __float2bfloat16(f);
    return *reinterpret_cast<ushort_t*>(&h);
}
__device__ __forceinline__ float bf2f(ushort_t u) {
    __hip_bfloat16 h = *reinterpret_cast<__hip_bfloat16*>(&u);
    return __bfloat162float(h);
}

// async 16B global -> LDS (LDS base wave-uniform; HW scatters lane*16)
__device__ __forceinline__ void load_lds16(const ushort_t* g, ushort_t* l) {
    __builtin_amdgcn_global_load_lds(
        (const __attribute__((address_space(1))) unsigned int*)g,
        (__attribute__((address_space(3))) unsigned int*)l,
        16, 0, 0);
}

// ---------------------------------------------------------------------------
// prep_all: x fp32->bf16 (blocks [0,4096)) + Wq/Wk/Wv transposing converts
// (blocks [4096,10240)) + zero AccBuf (blocks [10240,12288)) + zero AccL.
// ---------------------------------------------------------------------------
__global__ __launch_bounds__(256) void prep_all(const float* __restrict__ x,
                                                ushort_t* __restrict__ Xb,
                                                const float* __restrict__ Wq,
                                                const float* __restrict__ Wk,
                                                const float* __restrict__ Wv,
                                                ushort_t* __restrict__ WqkvT,
                                                f4* __restrict__ AccBuf4,
                                                f4* __restrict__ AccL4) {
    __shared__ float tile[32][33];
    const int b = blockIdx.x;
    if (b < 4096) {
        int i = (b * 256 + threadIdx.x) * 4;
        f4 v = *(const f4*)&x[i];
        Xb[i + 0] = f2bf(v[0]);
        Xb[i + 1] = f2bf(v[1]);
        Xb[i + 2] = f2bf(v[2]);
        Xb[i + 3] = f2bf(v[3]);
        return;
    }
    if (b >= 10240) {
        if (b < 12288) {
            int i = (b - 10240) * 256 + threadIdx.x;
            AccBuf4[i] = (f4){0.f, 0.f, 0.f, 0.f};
        } else {
            int i = (b - 12288) * 256 + threadIdx.x;
            if (i < 8192) AccL4[i] = (f4){0.f, 0.f, 0.f, 0.f};
        }
        return;
    }
    const float* src; int N, row_off, t;
    if (b < 8192)      { src = Wq; N = 2048; row_off = 0;    t = b - 4096; }
    else if (b < 9216) { src = Wk; N = 512;  row_off = 2048; t = b - 8192; }
    else               { src = Wv; N = 512;  row_off = 2560; t = b - 9216; }
    const int ntn = N / 32;
    const int n0 = (t % ntn) * 32, k0 = (t / ntn) * 32;
    const int tx = threadIdx.x & 31, ty = threadIdx.x >> 5;
    #pragma unroll
    for (int i = 0; i < 32; i += 8)
        tile[ty + i][tx] = src[(size_t)(k0 + ty + i) * N + (n0 + tx)];
    __syncthreads();
    #pragma unroll
    for (int i = 0; i < 32; i += 8)
        WqkvT[(size_t)(row_off + n0 + ty + i) * 2048 + (k0 + tx)] = f2bf(tile[tx][ty + i]);
}

// ---------------------------------------------------------------------------
// QKV GEMM with fused RMSNorm+RoPE (Q/K heads) and V^T write (V heads).
// Tile 128(M) x 64(N), BK=32, 4 waves at 64x32. BN=64 == one head.
// grid (48, 16): bx = head-column, by = row-tile.
//   bx <  32 : Q head bx      -> norm+rope -> QKVb cols [bx*64 ..)
//   32<=bx<40: K head bx-32   -> norm+rope -> QKVb cols [KCOL+(bx-32)*64 ..)
//   bx >= 40 : V head bx-40   -> direct reg->VTg transposed write
// ---------------------------------------------------------------------------
__global__ __launch_bounds__(256) void gemm_qkv(const ushort_t* __restrict__ A,
                                                const ushort_t* __restrict__ BT,
                                                ushort_t* __restrict__ QKVb,
                                                ushort_t* __restrict__ VTg,
                                                const float* __restrict__ gq,
                                                const float* __restrict__ gk,
                                                const float* __restrict__ cosT,
                                                const float* __restrict__ sinT) {
    __shared__ ushort_t SM[8448];                 // 16.9 KB union
    ushort_t (*As)[32] = (ushort_t(*)[32])SM;     // [128][32]
    ushort_t (*Bs)[32] = (ushort_t(*)[32])(SM + 4096);  // [64][32]
    ushort_t (*Epi)[66] = (ushort_t(*)[66])SM;    // [128][66] (post-loop alias)

    const int tid = threadIdx.x;
    const int w = tid >> 6, lane = tid & 63;
    const int r16 = lane & 15, quad = lane >> 4;
    const int wm = (w >> 1) * 64, wn = (w & 1) * 32;
    const int bm = blockIdx.y * 128;
    const int hcol = blockIdx.x;
    const int bn = hcol * 64;
    const int sr = lane >> 2;
    const int sc8 = (lane & 3) * 8;

    f32x4 acc[4][2];
    #pragma unroll
    for (int r = 0; r < 4; ++r)
        #pragma unroll
        for (int c = 0; c < 2; ++c) acc[r][c] = (f32x4){0.f, 0.f, 0.f, 0.f};

    for (int k0 = 0; k0 < 2048; k0 += 32) {
        __syncthreads();
        #pragma unroll
        for (int i = 0; i < 2; ++i) {
            int rowt = w * 32 + i * 16;
            load_lds16(A + (size_t)(bm + rowt + sr) * 2048 + k0 + sc8, &As[rowt][0]);
        }
        load_lds16(BT + (size_t)(bn + w * 16 + sr) * 2048 + k0 + sc8, &Bs[w * 16][0]);
        __syncthreads();

        bf16x8 af[4], bfr[2];
        #pragma unroll
        for (int r = 0; r < 4; ++r) af[r]  = *(const bf16x8*)&As[wm + 16 * r + r16][quad * 8];
        #pragma unroll
        for (int c = 0; c < 2; ++c) bfr[c] = *(const bf16x8*)&Bs[wn + 16 * c + r16][quad * 8];
        #pragma unroll
        for (int r = 0; r < 4; ++r)
            #pragma unroll
            for (int c = 0; c < 2; ++c)
                acc[r][c] = __builtin_amdgcn_mfma_f32_16x16x32_bf16(af[r], bfr[c], acc[r][c], 0, 0, 0);
    }

    if (hcol >= 40) {
        // ---- V head: direct transposed write from C-layout regs (8B packed)
        const int vd0 = (hcol - 40) * 64;
        #pragma unroll
        for (int r = 0; r < 4; ++r)
            #pragma unroll
            for (int c = 0; c < 2; ++c) {
                int col = wn + 16 * c + r16;          // head-dim
                int row0 = wm + 16 * r + quad * 4;    // seq
                us4 pk;
                #pragma unroll
                for (int reg = 0; reg < 4; ++reg) pk[reg] = f2bf(acc[r][c][reg]);
                *(us4*)&VTg[(size_t)(vd0 + col) * S + bm + row0] = pk;
            }
        return;
    }

    // ---- Q/K head: stash tile to LDS (bf16), then row-wise RMSNorm + RoPE
    __syncthreads();   // all waves done reading As/Bs
    #pragma unroll
    for (int r = 0; r < 4; ++r)
        #pragma unroll
        for (int c = 0; c < 2; ++c)
            #pragma unroll
            for (int reg = 0; reg < 4; ++reg)
                Epi[wm + 16 * r + quad * 4 + reg][wn + 16 * c + r16] = f2bf(acc[r][c][reg]);
    __syncthreads();

    const float* g = (hcol < 32) ? gq : gk;
    const int colbase = (hcol < 32) ? hcol * 64 : KCOL + (hcol - 32) * 64;
    const int row = tid >> 1;          // 0..127
    const int half = tid & 1;          // 0 or 1
    const int cbase = half * 32;
    const int s_glob = bm + row;

    float xv[32], pv[32];
    float ss = 0.f;
    #pragma unroll
    for (int j = 0; j < 32; ++j) {
        xv[j] = bf2f(Epi[row][cbase + j]);
        pv[j] = bf2f(Epi[row][(cbase ^ 32) + j]);
        ss += xv[j] * xv[j];
    }
    ss += __shfl_xor(ss, 1);           // partner thread (same row, other half)
    float inv = rsqrtf(ss * (1.0f / HD) + 1e-6f);

    ushort_t outp[32];
    #pragma unroll
    for (int j = 0; j < 32; ++j) {
        float xn = xv[j] * inv * g[cbase + j];
        float xp = pv[j] * inv * g[(cbase ^ 32) + j];
        float cs = cosT[(size_t)s_glob * HALF + j];
        float sn = sinT[(size_t)s_glob * HALF + j];
        float o = half ? (xp * sn + xn * cs) : (xn * cs - xp * sn);
        outp[j] = f2bf(o);
    }
    ushort_t* dst = QKVb + (size_t)s_glob * QKV_N + colbase + cbase;
    #pragma unroll
    for (int j = 0; j < 32; j += 8)
        *(bf16x8*)&dst[j] = *(const bf16x8*)&outp[j];
}

// ---------------------------------------------------------------------------
// bf16 MFMA GEMM, 64x64 tile, BK=64, 4 waves at 32x32 (out-proj).
// ---------------------------------------------------------------------------
template <typename OutT>
__global__ __launch_bounds__(256) void gemm64(const ushort_t* __restrict__ A,
                                              const ushort_t* __restrict__ BT,
                                              OutT* __restrict__ C,
                                              int M, int N, int Kdim) {
    __shared__ ushort_t As[64][64];
    __shared__ ushort_t Bs[64][64];
    const int tid = threadIdx.x;
    const int w = tid >> 6, lane = tid & 63;
    const int r16 = lane & 15, quad = lane >> 4;
    const int wm = (w >> 1) * 32, wn = (w & 1) * 32;
    const int bm = blockIdx.y * 64, bn = blockIdx.x * 64;
    const int srow = lane >> 3;
    const int jl = (lane & 7) ^ srow;
    const int rx = r16 & 7;

    f32x4 acc[2][2];
    #pragma unroll
    for (int r = 0; r < 2; ++r)
        #pragma unroll
        for (int c = 0; c < 2; ++c) acc[r][c] = (f32x4){0.f, 0.f, 0.f, 0.f};

    for (int k0 = 0; k0 < Kdim; k0 += 64) {
        __syncthreads();
        #pragma unroll
        for (int i = 0; i < 2; ++i) {
            int rbase = w * 16 + i * 8;
            load_lds16(A  + (size_t)(bm + rbase + srow) * Kdim + k0 + jl * 8, &As[rbase][0]);
            load_lds16(BT + (size_t)(bn + rbase + srow) * Kdim + k0 + jl * 8, &Bs[rbase][0]);
        }
        __syncthreads();

        #pragma unroll
        for (int h = 0; h < 2; ++h) {
            bf16x8 af[2], bfr[2];
            #pragma unroll
            for (int r = 0; r < 2; ++r)
                af[r]  = *(const bf16x8*)&As[wm + 16 * r + r16][((quad + 4 * h) ^ rx) * 8];
            #pragma unroll
            for (int c = 0; c < 2; ++c)
                bfr[c] = *(const bf16x8*)&Bs[wn + 16 * c + r16][((quad + 4 * h) ^ rx) * 8];
            #pragma unroll
            for (int r = 0; r < 2; ++r)
                #pragma unroll
                for (int c = 0; c < 2; ++c)
                    acc[r][c] = __builtin_amdgcn_mfma_f32_16x16x32_bf16(af[r], bfr[c], acc[r][c], 0, 0, 0);
        }
    }

    #pragma unroll
    for (int r = 0; r < 2; ++r)
        #pragma unroll
        for (int c = 0; c < 2; ++c)
            #pragma unroll
            for (int reg = 0; reg < 4; ++reg) {
                int row = bm + wm + 16 * r + quad * 4 + reg;
                int col = bn + wn + 16 * c + r16;
                float v = acc[r][c][reg];
                if constexpr (sizeof(OutT) == 2) C[(size_t)row * N + col] = (OutT)f2bf(v);
                else                             C[(size_t)row * N + col] = (OutT)v;
            }
}

// ---------------------------------------------------------------------------
// MFMA flash attention (R6 layout: 64-key tiles, 128B Vt rows). grid (48, NQ).
//   bx <  16: qt = 16+bx, tiles [0,16)  -> atomic partial
//   bx >= 16: qt = 47-bx; qt>=16: [16,qt+1) atomic; qt<16: [0,qt+1) direct
// ---------------------------------------------------------------------------
__global__ __launch_bounds__(256) void flash_attn_mfma(const ushort_t* __restrict__ QKV,
                                                       const ushort_t* __restrict__ VTg,
                                                       ushort_t* __restrict__ O,
                                                       float* __restrict__ AccBuf,
                                                       float* __restrict__ AccL) {
    __shared__ ushort_t Ks[2][64][64];
    __shared__ ushort_t Vt[2][64][64];
    __shared__ ushort_t Ps[4][16][72];

    const int bx = blockIdx.x;
    int qt, tb, te;
    bool atom;
    if (bx < 16) { qt = 16 + bx; tb = 0; te = 16; atom = true; }
    else         { qt = 47 - bx; atom = (qt >= 16); tb = atom ? 16 : 0; te = qt + 1; }

    const int q0 = qt * 64;
    const int h  = blockIdx.y;
    const int kvh = h >> 2;
    const int tid = threadIdx.x;
    const int w = tid >> 6, lane = tid & 63;
    const int r16 = lane & 15, quad = lane >> 4;
    const int kcol = KCOL + kvh * HD;
    const int vtrow0 = kvh * HD;
    const int rsub = lane >> 3;
    const int jlog = (lane & 7) ^ rsub;
    const int rx = r16 & 7;

    const ushort_t* qrow = QKV + (size_t)(q0 + 16 * w + r16) * QKV_N + h * HD;
    bf16x8 qf0, qf1;
    {
        bf16x8 r0 = *(const bf16x8*)(qrow + quad * 8);
        bf16x8 r1 = *(const bf16x8*)(qrow + quad * 8 + 32);
        #pragma unroll
        for (int j = 0; j < 8; ++j) {
            qf0[j] = (short)f2bf(bf2f((ushort_t)r0[j]) * 0.18033688f);
            qf1[j] = (short)f2bf(bf2f((ushort_t)r1[j]) * 0.18033688f);
        }
    }

    bf16x8 onesf;
    {
        ushort_t ov = (r16 == 0) ? (ushort_t)0x3F80 : (ushort_t)0;
        #pragma unroll
        for (int j = 0; j < 8; ++j) onesf[j] = (short)ov;
    }

    f32x4 accO[4];
    f32x4 accL = (f32x4){0.f, 0.f, 0.f, 0.f};
    #pragma unroll
    for (int c = 0; c < 4; ++c) accO[c] = (f32x4){0.f, 0.f, 0.f, 0.f};

    auto stage = [&](int b, int t0) {
        #pragma unroll
        for (int i = 0; i < 2; ++i) {
            int base = w * 16 + i * 8;
            int row = base + rsub;
            load_lds16(QKV + (size_t)(t0 + row) * QKV_N + kcol + jlog * 8, &Ks[b][base][0]);
            load_lds16(VTg + (size_t)(vtrow0 + row) * S + t0 + jlog * 8, &Vt[b][base][0]);
        }
    };

    stage(tb & 1, tb * 64);

    for (int t = tb; t < te; ++t) {
        __syncthreads();
        if (t + 1 < te) stage((t + 1) & 1, (t + 1) * 64);

        const ushort_t (*K_)[64] = Ks[t & 1];
        const ushort_t (*V_)[64] = Vt[t & 1];
        const bool diag = (t == qt);

        f32x4 sc[4];
        #pragma unroll
        for (int c = 0; c < 4; ++c) {
            bf16x8 kf0 = *(const bf16x8*)&K_[16 * c + r16][(quad ^ rx) * 8];
            bf16x8 kf1 = *(const bf16x8*)&K_[16 * c + r16][((quad + 4) ^ rx) * 8];
            f32x4 z = (f32x4){0.f, 0.f, 0.f, 0.f};
            z = __builtin_amdgcn_mfma_f32_16x16x32_bf16(qf0, kf0, z, 0, 0, 0);
            z = __builtin_amdgcn_mfma_f32_16x16x32_bf16(qf1, kf1, z, 0, 0, 0);
            sc[c] = z;
        }

        #pragma unroll
        for (int c = 0; c < 4; ++c)
            #pragma unroll
            for (int reg = 0; reg < 4; ++reg) {
                float v = sc[c][reg];
                if (diag && (16 * c + r16 > 16 * w + quad * 4 + reg)) v = -INFINITY;
                Ps[w][quad * 4 + reg][16 * c + r16] = f2bf(exp2f(v));
            }

        bf16x8 pf0 = *(const bf16x8*)&Ps[w][r16][quad * 8];
        bf16x8 pf1 = *(const bf16x8*)&Ps[w][r16][quad * 8 + 32];

        accL = __builtin_amdgcn_mfma_f32_16x16x32_bf16(pf0, onesf, accL, 0, 0, 0);
        accL = __builtin_amdgcn_mfma_f32_16x16x32_bf16(pf1, onesf, accL, 0, 0, 0);

        #pragma unroll
        for (int c = 0; c < 4; ++c) {
            bf16x8 vf0 = *(const bf16x8*)&V_[16 * c + r16][(quad ^ rx) * 8];
            bf16x8 vf1 = *(const bf16x8*)&V_[16 * c + r16][((quad + 4) ^ rx) * 8];
            accO[c] = __builtin_amdgcn_mfma_f32_16x16x32_bf16(pf0, vf0, accO[c], 0, 0, 0);
            accO[c] = __builtin_amdgcn_mfma_f32_16x16x32_bf16(pf1, vf1, accO[c], 0, 0, 0);
        }
    }

    if (!atom) {
        #pragma unroll
        for (int reg = 0; reg < 4; ++reg) {
            float l = __shfl(accL[reg], lane & 48);
            float invl = 1.0f / l;
            int row = q0 + 16 * w + quad * 4 + reg;
            ushort_t* op = O + (size_t)row * D + h * HD;
            #pragma unroll
            for (int c = 0; c < 4; ++c)
                op[16 * c + r16] = f2bf(accO[c][reg] * invl);
        }
    } else {
        const int pair = (qt - 16) * 32 + h;
        float* ab = AccBuf + (size_t)pair * 4096;
        #pragma unroll
        for (int reg = 0; reg < 4; ++reg) {
            int row = 16 * w + quad * 4 + reg;
            #pragma unroll
            for (int c = 0; c < 4; ++c)
                atomicAdd(&ab[row * 64 + 16 * c + r16], accO[c][reg]);
        }
        if (r16 == 0) {
            #pragma unroll
            for (int reg = 0; reg < 4; ++reg)
                atomicAdd(&AccL[pair * 64 + 16 * w + quad * 4 + reg], accL[reg]);
        }
    }
}

// ---------------------------------------------------------------------------
// normalize split-K partials (blocks [0,512)) + Wo transpose-convert
// (blocks [512, 512+4096)) into the now-dead WqkvT region.
// ---------------------------------------------------------------------------
__global__ __launch_bounds__(256) void normalize_wo(const float* __restrict__ AccBuf,
                                                    const float* __restrict__ AccL,
                                                    ushort_t* __restrict__ O,
                                                    const float* __restrict__ Wo,
                                                    ushort_t* __restrict__ WoT) {
    const int b = blockIdx.x;
    if (b < 512) {
        const int qt = 16 + (b >> 5);
        const int h  = b & 31;
        const float* ab = AccBuf + (size_t)b * 4096;
        const float* lp = AccL + b * 64;
        for (int i = threadIdx.x; i < 4096; i += 256) {
            int row = i >> 6, d = i & 63;
            O[(size_t)(qt * 64 + row) * D + h * HD + d] = f2bf(ab[i] / lp[row]);
        }
        return;
    }
    __shared__ float wt[32][33];
    const int idx = b - 512;
    const int n0 = (idx & 63) * 32, k0 = (idx >> 6) * 32;
    const int tx = threadIdx.x & 31, ty = threadIdx.x >> 5;
    #pragma unroll
    for (int i = 0; i < 32; i += 8)
        wt[ty + i][tx] = Wo[(size_t)(k0 + ty + i) * 2048 + (n0 + tx)];
    __syncthreads();
    #pragma unroll
    for (int i = 0; i < 32; i += 8)
        WoT[(size_t)(n0 + ty + i) * 2048 + (k0 + tx)] = f2bf(wt[tx][ty + i]);
}

// ---------------------------------------------------------------------------
// Memory plan:
//   ws[ 0M, 8M)  Xb (x bf16)   -> dead after QKV GEMM -> Ob
//   ws[ 8M,20M)  WqkvT         -> dead after QKV GEMM -> WoT at [8M,16M)
//   ws[20M,32M)  QKVb
//   d_out[ 0M, 8M)   AccBuf (fp32 split-K partials)
//   d_out[ 8M,10M)   VTg  (bf16 [512][2048])
//   d_out[10M,10.13M) AccL
//   (out-proj overwrites all of d_out at the end)
// ---------------------------------------------------------------------------
extern "C" void kernel_launch(void* const* d_in, const int* in_sizes, int n_in,
                              void* d_out, int out_size, void* d_ws, size_t ws_size,
                              hipStream_t stream) {
    const float* x    = (const float*)d_in[0];
    const float* cosT = (const float*)d_in[1];
    const float* sinT = (const float*)d_in[2];
    const float* g_q  = (const float*)d_in[3];
    const float* g_k  = (const float*)d_in[4];
    const float* Wq   = (const float*)d_in[5];
    const float* Wk   = (const float*)d_in[6];
    const float* Wv   = (const float*)d_in[7];
    const float* Wo   = (const float*)d_in[8];
    float* out = (float*)d_out;

    char* base = (char*)d_ws;
    char* ob   = (char*)d_out;
    ushort_t* Xb     = (ushort_t*)base;
    ushort_t* WqkvT  = (ushort_t*)(base + 8388608);
    ushort_t* QKVb   = (ushort_t*)(base + 20971520);
    ushort_t* WoT    = (ushort_t*)(base + 8388608);   // alias dead WqkvT
    ushort_t* Ob     = Xb;                             // alias dead Xb
    float*    AccBuf = (float*)ob;                     // d_out[0,8M)
    ushort_t* VTg    = (ushort_t*)(ob + 8388608);      // d_out[8M,10M)
    float*    AccL   = (float*)(ob + 10485760);        // d_out[10M,+128K)

    // 1. x convert + Wq/Wk/Wv transpose + zero accumulators
    prep_all<<<12320, 256, 0, stream>>>(x, Xb, Wq, Wk, Wv, WqkvT, (f4*)AccBuf, (f4*)AccL);
    // 2. QKV projection with fused RMSNorm+RoPE and V^T epilogue
    gemm_qkv<<<dim3(48, 16), 256, 0, stream>>>(Xb, WqkvT, QKVb, VTg, g_q, g_k, cosT, sinT);
    // 3. split-K MFMA flash attention
    flash_attn_mfma<<<dim3(48, NQ), 256, 0, stream>>>(QKVb, VTg, Ob, AccBuf, AccL);
    // 4. combine split-K partials + Wo transpose (WqkvT now dead)
    normalize_wo<<<4608, 256, 0, stream>>>(AccBuf, AccL, Ob, Wo, WoT);
    // 5. output projection (fp32, overwrites d_out scratch regions)
    gemm64<float><<<dim3(D / 64, S / 64), 256, 0, stream>>>(Ob, WoT, out, S, D, D);
}

// Round 9
// 250.239 us; speedup vs baseline: 1.0821x; 1.0821x over previous
//
#include <hip/hip_runtime.h>
#include <hip/hip_bf16.h>
#include <math.h>

#define S 2048
#define D 2048
#define NQ 32
#define NKV 8
#define HD 64
#define HALF 32
#define NREP 4
#define QKV_N 3072           // NQ*HD + 2*NKV*HD
#define KCOL 2048            // K starts here in fused QKV buffer
#define VCOL 2560            // V starts here

typedef unsigned short ushort_t;
typedef __attribute__((ext_vector_type(8))) short bf16x8;   // 8 bf16 = 4 VGPRs
typedef __attribute__((ext_vector_type(4))) float f32x4;
typedef float f4 __attribute__((ext_vector_type(4)));

__device__ __forceinline__ ushort_t f2bf(float f) {
    __hip_bfloat16 h = __float2bfloat16(f);
    return *reinterpret_cast<ushort_t*>(&h);
}
__device__ __forceinline__ float bf2f(ushort_t u) {
    __hip_bfloat16 h = *reinterpret_cast<__hip_bfloat16*>(&u);
    return __bfloat162float(h);
}

// async 16B global -> LDS (LDS base wave-uniform; HW scatters lane*16)
__device__ __forceinline__ void load_lds16(const ushort_t* g, ushort_t* l) {
    __builtin_amdgcn_global_load_lds(
        (const __attribute__((address_space(1))) unsigned int*)g,
        (__attribute__((address_space(3))) unsigned int*)l,
        16, 0, 0);
}

// ---------------------------------------------------------------------------
// prep_all: x fp32->bf16 (blocks [0,4096)) + Wq/Wk/Wv transposing converts
// into fused WqkvT [3072,2048] (blocks [4096,10240)).
// ---------------------------------------------------------------------------
__global__ __launch_bounds__(256) void prep_all(const float* __restrict__ x,
                                                ushort_t* __restrict__ Xb,
                                                const float* __restrict__ Wq,
                                                const float* __restrict__ Wk,
                                                const float* __restrict__ Wv,
                                                ushort_t* __restrict__ WqkvT) {
    __shared__ float tile[32][33];
    const int b = blockIdx.x;
    if (b < 4096) {
        int i = (b * 256 + threadIdx.x) * 4;
        f4 v = *(const f4*)&x[i];
        Xb[i + 0] = f2bf(v[0]);
        Xb[i + 1] = f2bf(v[1]);
        Xb[i + 2] = f2bf(v[2]);
        Xb[i + 3] = f2bf(v[3]);
        return;
    }
    const float* src; int N, row_off, t;
    if (b < 8192)      { src = Wq; N = 2048; row_off = 0;    t = b - 4096; }
    else if (b < 9216) { src = Wk; N = 512;  row_off = 2048; t = b - 8192; }
    else               { src = Wv; N = 512;  row_off = 2560; t = b - 9216; }
    const int ntn = N / 32;
    const int n0 = (t % ntn) * 32, k0 = (t / ntn) * 32;
    const int tx = threadIdx.x & 31, ty = threadIdx.x >> 5;
    #pragma unroll
    for (int i = 0; i < 32; i += 8)
        tile[ty + i][tx] = src[(size_t)(k0 + ty + i) * N + (n0 + tx)];
    __syncthreads();
    #pragma unroll
    for (int i = 0; i < 32; i += 8)
        WqkvT[(size_t)(row_off + n0 + ty + i) * 2048 + (k0 + tx)] = f2bf(tile[tx][ty + i]);
}

// ---------------------------------------------------------------------------
// Split-K QKV GEMM (m97 128x128 structure, BK=32). grid (24, 16, 2).
// blockIdx.z selects K-half [z*1024, z*1024+1024); writes bf16 partial
// P0 (z=0) or P1 (z=1), layout [2048][3072].
// ---------------------------------------------------------------------------
__global__ __launch_bounds__(256) void gemm_qkv_sk(const ushort_t* __restrict__ A,
                                                   const ushort_t* __restrict__ BT,
                                                   ushort_t* __restrict__ P0,
                                                   ushort_t* __restrict__ P1) {
    __shared__ ushort_t As[128][32];
    __shared__ ushort_t Bs[128][32];
    const int tid = threadIdx.x;
    const int w = tid >> 6, lane = tid & 63;
    const int r16 = lane & 15, quad = lane >> 4;
    const int wm = (w >> 1) * 64, wn = (w & 1) * 64;
    const int bm = blockIdx.y * 128, bn = blockIdx.x * 128;
    const int sr = lane >> 2;
    const int sc8 = (lane & 3) * 8;
    const int kbeg = blockIdx.z * 1024;
    ushort_t* P = blockIdx.z ? P1 : P0;

    f32x4 acc[4][4];
    #pragma unroll
    for (int r = 0; r < 4; ++r)
        #pragma unroll
        for (int c = 0; c < 4; ++c) acc[r][c] = (f32x4){0.f, 0.f, 0.f, 0.f};

    for (int k0 = kbeg; k0 < kbeg + 1024; k0 += 32) {
        __syncthreads();
        #pragma unroll
        for (int i = 0; i < 2; ++i) {
            int rowt = w * 32 + i * 16;
            load_lds16(A  + (size_t)(bm + rowt + sr) * 2048 + k0 + sc8, &As[rowt][0]);
            load_lds16(BT + (size_t)(bn + rowt + sr) * 2048 + k0 + sc8, &Bs[rowt][0]);
        }
        __syncthreads();

        bf16x8 af[4], bfr[4];
        #pragma unroll
        for (int r = 0; r < 4; ++r) af[r]  = *(const bf16x8*)&As[wm + 16 * r + r16][quad * 8];
        #pragma unroll
        for (int c = 0; c < 4; ++c) bfr[c] = *(const bf16x8*)&Bs[wn + 16 * c + r16][quad * 8];
        #pragma unroll
        for (int r = 0; r < 4; ++r)
            #pragma unroll
            for (int c = 0; c < 4; ++c)
                acc[r][c] = __builtin_amdgcn_mfma_f32_16x16x32_bf16(af[r], bfr[c], acc[r][c], 0, 0, 0);
    }

    #pragma unroll
    for (int r = 0; r < 4; ++r)
        #pragma unroll
        for (int c = 0; c < 4; ++c)
            #pragma unroll
            for (int reg = 0; reg < 4; ++reg) {
                int row = bm + wm + 16 * r + quad * 4 + reg;
                int col = bn + wn + 16 * c + r16;
                P[(size_t)row * QKV_N + col] = f2bf(acc[r][c][reg]);
            }
}

// ---------------------------------------------------------------------------
// combine: P0+P1 -> RMSNorm+RoPE for Q/K (y<10, in-place into QKVb=P0),
// V^T = P0+P1 transposed (y==10, xb<1024), Wo transpose-convert (rest).
// grid (2048, 13).
// ---------------------------------------------------------------------------
__global__ __launch_bounds__(256) void combine_qkv(ushort_t* __restrict__ QKVb,   // = P0
                                                   const ushort_t* __restrict__ P1,
                                                   const float* __restrict__ gq,
                                                   const float* __restrict__ gk,
                                                   const float* __restrict__ cosT,
                                                   const float* __restrict__ sinT,
                                                   ushort_t* __restrict__ VTg,
                                                   const float* __restrict__ Wo,
                                                   ushort_t* __restrict__ WoT) {
    const int y = blockIdx.y, xb = blockIdx.x;
    if (y < 10) {
        const int s = xb;
        const int w = threadIdx.x >> 6;
        const int hh = y * 4 + w;
        const int d = threadIdx.x & 63;
        const float* g;
        int col;
        if (hh < NQ) { g = gq; col = hh * HD; }
        else         { g = gk; col = KCOL + (hh - NQ) * HD; }
        ushort_t* xp = QKVb + (size_t)s * QKV_N + col;
        const ushort_t* xp1 = P1 + (size_t)s * QKV_N + col;
        float v = bf2f(xp[d]) + bf2f(xp1[d]);
        float ss = v * v;
        #pragma unroll
        for (int off = 32; off > 0; off >>= 1) ss += __shfl_down(ss, off);
        ss = __shfl(ss, 0);
        float inv = rsqrtf(ss * (1.0f / HD) + 1e-6f);
        float xn = v * inv * g[d];
        float other = __shfl(xn, d ^ 32);
        float c = cosT[(size_t)s * HALF + (d & 31)];
        float sn = sinT[(size_t)s * HALF + (d & 31)];
        float outv = (d < HALF) ? (xn * c - other * sn) : (other * sn + xn * c);
        xp[d] = f2bf(outv);
        return;
    }
    const int tx = threadIdx.x & 31, ty = threadIdx.x >> 5;
    if (y == 10 && xb < 1024) {
        __shared__ ushort_t vt[32][33];
        const int s0 = (xb & 63) * 32, d0 = (xb >> 6) * 32;
        #pragma unroll
        for (int i = 0; i < 32; i += 8) {
            size_t idx = (size_t)(s0 + ty + i) * QKV_N + VCOL + d0 + tx;
            vt[ty + i][tx] = f2bf(bf2f(QKVb[idx]) + bf2f(P1[idx]));
        }
        __syncthreads();
        #pragma unroll
        for (int i = 0; i < 32; i += 8)
            VTg[(size_t)(d0 + ty + i) * S + s0 + tx] = vt[tx][ty + i];
        return;
    }
    int idx;
    if (y == 10)      idx = xb - 1024;
    else if (y == 11) idx = 1024 + xb;
    else              idx = 3072 + xb;
    if (idx < 0 || idx >= 4096) return;
    __shared__ float wt[32][33];
    const int n0 = (idx & 63) * 32, k0 = (idx >> 6) * 32;
    #pragma unroll
    for (int i = 0; i < 32; i += 8)
        wt[ty + i][tx] = Wo[(size_t)(k0 + ty + i) * 2048 + (n0 + tx)];
    __syncthreads();
    #pragma unroll
    for (int i = 0; i < 32; i += 8)
        WoT[(size_t)(n0 + ty + i) * 2048 + (k0 + tx)] = f2bf(wt[tx][ty + i]);
}

// ---------------------------------------------------------------------------
// zero AccBuf (8 MB) + AccL (128 KB). Must run AFTER combine (AccBuf
// overlaps the P1 region of d_out).
// ---------------------------------------------------------------------------
__global__ __launch_bounds__(256) void zero_acc(f4* __restrict__ AccBuf4,
                                                f4* __restrict__ AccL4) {
    int i = blockIdx.x * 256 + threadIdx.x;
    if (i < 524288) AccBuf4[i] = (f4){0.f, 0.f, 0.f, 0.f};
    else if (i < 532480) AccL4[i - 524288] = (f4){0.f, 0.f, 0.f, 0.f};
}

// ---------------------------------------------------------------------------
// MFMA flash attention v5: split-K causal GQA, TWO Q-heads per block
// (pairs share kvh). grid (48, 16), block 256 = 4 waves, 50 KB LDS
// (3 blocks/CU). bx mapping as before:
//   bx <  16: qt = 16+bx, tiles [0,16)  -> atomic partial
//   bx >= 16: qt = 47-bx; qt>=16: [16,qt+1) atomic; qt<16: [0,qt+1) direct
// ---------------------------------------------------------------------------
__global__ __launch_bounds__(256) void flash_attn_mfma(const ushort_t* __restrict__ QKV,
                                                       const ushort_t* __restrict__ VTg,
                                                       ushort_t* __restrict__ O,
                                                       float* __restrict__ AccBuf,
                                                       float* __restrict__ AccL) {
    __shared__ ushort_t Ks[2][64][64];       // 16 KB
    __shared__ ushort_t Vt[2][64][64];       // 16 KB
    __shared__ ushort_t Ps[2][4][16][72];    // 18 KB, [head][wave][row][key]

    const int bx = blockIdx.x;
    int qt, tb, te;
    bool atom;
    if (bx < 16) { qt = 16 + bx; tb = 0; te = 16; atom = true; }
    else         { qt = 47 - bx; atom = (qt >= 16); tb = atom ? 16 : 0; te = qt + 1; }

    const int q0 = qt * 64;
    const int hy = blockIdx.y;
    const int h0 = hy * 2;
    const int kvh = hy >> 1;
    const int tid = threadIdx.x;
    const int w = tid >> 6, lane = tid & 63;
    const int r16 = lane & 15, quad = lane >> 4;
    const int kcol = KCOL + kvh * HD;
    const int vtrow0 = kvh * HD;
    const int rsub = lane >> 3;
    const int jlog = (lane & 7) ^ rsub;
    const int rx = r16 & 7;

    // Q fragments for both heads (A-layout), prescaled by 1/sqrt(HD)*log2(e)
    bf16x8 qf[2][2];
    #pragma unroll
    for (int e = 0; e < 2; ++e) {
        const ushort_t* qrow = QKV + (size_t)(q0 + 16 * w + r16) * QKV_N + (h0 + e) * HD;
        bf16x8 r0 = *(const bf16x8*)(qrow + quad * 8);
        bf16x8 r1 = *(const bf16x8*)(qrow + quad * 8 + 32);
        #pragma unroll
        for (int j = 0; j < 8; ++j) {
            qf[e][0][j] = (short)f2bf(bf2f((ushort_t)r0[j]) * 0.18033688f);
            qf[e][1][j] = (short)f2bf(bf2f((ushort_t)r1[j]) * 0.18033688f);
        }
    }

    bf16x8 onesf;
    {
        ushort_t ov = (r16 == 0) ? (ushort_t)0x3F80 : (ushort_t)0;
        #pragma unroll
        for (int j = 0; j < 8; ++j) onesf[j] = (short)ov;
    }

    f32x4 accO[2][4];
    f32x4 accL2[2];
    #pragma unroll
    for (int e = 0; e < 2; ++e) {
        accL2[e] = (f32x4){0.f, 0.f, 0.f, 0.f};
        #pragma unroll
        for (int c = 0; c < 4; ++c) accO[e][c] = (f32x4){0.f, 0.f, 0.f, 0.f};
    }

    auto stage = [&](int b, int t0) {
        #pragma unroll
        for (int i = 0; i < 2; ++i) {
            int base = w * 16 + i * 8;
            int row = base + rsub;
            load_lds16(QKV + (size_t)(t0 + row) * QKV_N + kcol + jlog * 8, &Ks[b][base][0]);
            load_lds16(VTg + (size_t)(vtrow0 + row) * S + t0 + jlog * 8, &Vt[b][base][0]);
        }
    };

    stage(tb & 1, tb * 64);

    for (int t = tb; t < te; ++t) {
        __syncthreads();
        if (t + 1 < te) stage((t + 1) & 1, (t + 1) * 64);

        const ushort_t (*K_)[64] = Ks[t & 1];
        const ushort_t (*V_)[64] = Vt[t & 1];
        const bool diag = (t == qt);

        // ---- S = Qs K^T for both heads (K fragments shared)
        f32x4 sc[2][4];
        #pragma unroll
        for (int c = 0; c < 4; ++c) {
            bf16x8 kf0 = *(const bf16x8*)&K_[16 * c + r16][(quad ^ rx) * 8];
            bf16x8 kf1 = *(const bf16x8*)&K_[16 * c + r16][((quad + 4) ^ rx) * 8];
            #pragma unroll
            for (int e = 0; e < 2; ++e) {
                f32x4 z = (f32x4){0.f, 0.f, 0.f, 0.f};
                z = __builtin_amdgcn_mfma_f32_16x16x32_bf16(qf[e][0], kf0, z, 0, 0, 0);
                z = __builtin_amdgcn_mfma_f32_16x16x32_bf16(qf[e][1], kf1, z, 0, 0, 0);
                sc[e][c] = z;
            }
        }

        // ---- p = exp2(s), causal mask, store to Ps (C->A layout)
        #pragma unroll
        for (int e = 0; e < 2; ++e)
            #pragma unroll
            for (int c = 0; c < 4; ++c)
                #pragma unroll
                for (int reg = 0; reg < 4; ++reg) {
                    float v = sc[e][c][reg];
                    if (diag && (16 * c + r16 > 16 * w + quad * 4 + reg)) v = -INFINITY;
                    Ps[e][w][quad * 4 + reg][16 * c + r16] = f2bf(exp2f(v));
                }

        bf16x8 pf0[2], pf1[2];
        #pragma unroll
        for (int e = 0; e < 2; ++e) {
            pf0[e] = *(const bf16x8*)&Ps[e][w][r16][quad * 8];
            pf1[e] = *(const bf16x8*)&Ps[e][w][r16][quad * 8 + 32];
            accL2[e] = __builtin_amdgcn_mfma_f32_16x16x32_bf16(pf0[e], onesf, accL2[e], 0, 0, 0);
            accL2[e] = __builtin_amdgcn_mfma_f32_16x16x32_bf16(pf1[e], onesf, accL2[e], 0, 0, 0);
        }

        // ---- O += P V for both heads (V fragments shared)
        #pragma unroll
        for (int c = 0; c < 4; ++c) {
            bf16x8 vf0 = *(const bf16x8*)&V_[16 * c + r16][(quad ^ rx) * 8];
            bf16x8 vf1 = *(const bf16x8*)&V_[16 * c + r16][((quad + 4) ^ rx) * 8];
            #pragma unroll
            for (int e = 0; e < 2; ++e) {
                accO[e][c] = __builtin_amdgcn_mfma_f32_16x16x32_bf16(pf0[e], vf0, accO[e][c], 0, 0, 0);
                accO[e][c] = __builtin_amdgcn_mfma_f32_16x16x32_bf16(pf1[e], vf1, accO[e][c], 0, 0, 0);
            }
        }
    }

    #pragma unroll
    for (int e = 0; e < 2; ++e) {
        const int h = h0 + e;
        if (!atom) {
            #pragma unroll
            for (int reg = 0; reg < 4; ++reg) {
                float l = __shfl(accL2[e][reg], lane & 48);
                float invl = 1.0f / l;
                int row = q0 + 16 * w + quad * 4 + reg;
                ushort_t* op = O + (size_t)row * D + h * HD;
                #pragma unroll
                for (int c = 0; c < 4; ++c)
                    op[16 * c + r16] = f2bf(accO[e][c][reg] * invl);
            }
        } else {
            const int pair = (qt - 16) * 32 + h;
            float* ab = AccBuf + (size_t)pair * 4096;
            #pragma unroll
            for (int reg = 0; reg < 4; ++reg) {
                int row = 16 * w + quad * 4 + reg;
                #pragma unroll
                for (int c = 0; c < 4; ++c)
                    atomicAdd(&ab[row * 64 + 16 * c + r16], accO[e][c][reg]);
            }
            if (r16 == 0) {
                #pragma unroll
                for (int reg = 0; reg < 4; ++reg)
                    atomicAdd(&AccL[pair * 64 + 16 * w + quad * 4 + reg], accL2[e][reg]);
            }
        }
    }
}

// ---------------------------------------------------------------------------
// Combine split-K attention partials: O = AccBuf / AccL for qt in [16,32).
// ---------------------------------------------------------------------------
__global__ __launch_bounds__(256) void normalize_o(const float* __restrict__ AccBuf,
                                                   const float* __restrict__ AccL,
                                                   ushort_t* __restrict__ O) {
    const int b = blockIdx.x;
    const int qt = 16 + (b >> 5);
    const int h  = b & 31;
    const float* ab = AccBuf + (size_t)b * 4096;
    const float* lp = AccL + b * 64;
    for (int i = threadIdx.x; i < 4096; i += 256) {
        int row = i >> 6, d = i & 63;
        O[(size_t)(qt * 64 + row) * D + h * HD + d] = f2bf(ab[i] / lp[row]);
    }
}

// ---------------------------------------------------------------------------
// bf16 MFMA GEMM, 64x64 tile, BK=64 (out-proj), 1024 blocks.
// ---------------------------------------------------------------------------
__global__ __launch_bounds__(256) void gemm64_f(const ushort_t* __restrict__ A,
                                                const ushort_t* __restrict__ BT,
                                                float* __restrict__ C,
                                                int M, int N, int Kdim) {
    __shared__ ushort_t As[64][64];
    __shared__ ushort_t Bs[64][64];
    const int tid = threadIdx.x;
    const int w = tid >> 6, lane = tid & 63;
    const int r16 = lane & 15, quad = lane >> 4;
    const int wm = (w >> 1) * 32, wn = (w & 1) * 32;
    const int bm = blockIdx.y * 64, bn = blockIdx.x * 64;
    const int srow = lane >> 3;
    const int jl = (lane & 7) ^ srow;
    const int rx = r16 & 7;

    f32x4 acc[2][2];
    #pragma unroll
    for (int r = 0; r < 2; ++r)
        #pragma unroll
        for (int c = 0; c < 2; ++c) acc[r][c] = (f32x4){0.f, 0.f, 0.f, 0.f};

    for (int k0 = 0; k0 < Kdim; k0 += 64) {
        __syncthreads();
        #pragma unroll
        for (int i = 0; i < 2; ++i) {
            int rbase = w * 16 + i * 8;
            load_lds16(A  + (size_t)(bm + rbase + srow) * Kdim + k0 + jl * 8, &As[rbase][0]);
            load_lds16(BT + (size_t)(bn + rbase + srow) * Kdim + k0 + jl * 8, &Bs[rbase][0]);
        }
        __syncthreads();

        #pragma unroll
        for (int hh = 0; hh < 2; ++hh) {
            bf16x8 af[2], bfr[2];
            #pragma unroll
            for (int r = 0; r < 2; ++r)
                af[r]  = *(const bf16x8*)&As[wm + 16 * r + r16][((quad + 4 * hh) ^ rx) * 8];
            #pragma unroll
            for (int c = 0; c < 2; ++c)
                bfr[c] = *(const bf16x8*)&Bs[wn + 16 * c + r16][((quad + 4 * hh) ^ rx) * 8];
            #pragma unroll
            for (int r = 0; r < 2; ++r)
                #pragma unroll
                for (int c = 0; c < 2; ++c)
                    acc[r][c] = __builtin_amdgcn_mfma_f32_16x16x32_bf16(af[r], bfr[c], acc[r][c], 0, 0, 0);
        }
    }

    #pragma unroll
    for (int r = 0; r < 2; ++r)
        #pragma unroll
        for (int c = 0; c < 2; ++c)
            #pragma unroll
            for (int reg = 0; reg < 4; ++reg) {
                int row = bm + wm + 16 * r + quad * 4 + reg;
                int col = bn + wn + 16 * c + r16;
                C[(size_t)row * N + col] = acc[r][c][reg];
            }
}

// ---------------------------------------------------------------------------
// Memory plan:
//   ws[ 0M, 8M)  Xb (x bf16)  -> dead after QKV GEMM -> Ob
//   ws[ 8M,20M)  WqkvT        -> dead after QKV GEMM -> WoT at [8M,16M)
//   ws[20M,32M)  QKVb = P0 (split-K partial, combined in place)
//   d_out[0,12.6M)        P1 (split-K partial)  -> dead after combine
//   d_out[0,8M)           AccBuf (zeroed after combine)
//   d_out[12.6M,14.7M)    VTg
//   d_out[14.7M,+128K)    AccL
//   out-proj overwrites all 16 MB of d_out at the end.
// ---------------------------------------------------------------------------
extern "C" void kernel_launch(void* const* d_in, const int* in_sizes, int n_in,
                              void* d_out, int out_size, void* d_ws, size_t ws_size,
                              hipStream_t stream) {
    const float* x    = (const float*)d_in[0];
    const float* cosT = (const float*)d_in[1];
    const float* sinT = (const float*)d_in[2];
    const float* g_q  = (const float*)d_in[3];
    const float* g_k  = (const float*)d_in[4];
    const float* Wq   = (const float*)d_in[5];
    const float* Wk   = (const float*)d_in[6];
    const float* Wv   = (const float*)d_in[7];
    const float* Wo   = (const float*)d_in[8];
    float* out = (float*)d_out;

    char* base = (char*)d_ws;
    char* ob   = (char*)d_out;
    ushort_t* Xb     = (ushort_t*)base;
    ushort_t* WqkvT  = (ushort_t*)(base + 8388608);
    ushort_t* QKVb   = (ushort_t*)(base + 20971520);     // = P0
    ushort_t* WoT    = (ushort_t*)(base + 8388608);      // alias dead WqkvT
    ushort_t* Ob     = Xb;                                // alias dead Xb
    ushort_t* P1     = (ushort_t*)ob;                     // d_out[0,12.6M)
    float*    AccBuf = (float*)ob;                        // d_out[0,8M), post-combine
    ushort_t* VTg    = (ushort_t*)(ob + 12582912);        // d_out[12.6M,14.7M)
    float*    AccL   = (float*)(ob + 14680064);           // d_out[14.7M,+128K)

    // 1. x convert + Wq/Wk/Wv transpose-convert
    prep_all<<<10240, 256, 0, stream>>>(x, Xb, Wq, Wk, Wv, WqkvT);
    // 2. split-K QKV projection (768 blocks, 3/CU)
    gemm_qkv_sk<<<dim3(24, 16, 2), 256, 0, stream>>>(Xb, WqkvT, QKVb, P1);
    // 3. combine partials + RMSNorm+RoPE + V^T + Wo transpose
    combine_qkv<<<dim3(2048, 13), 256, 0, stream>>>(QKVb, P1, g_q, g_k, cosT, sinT, VTg, Wo, WoT);
    // 4. zero split-K attention accumulators (P1 region now dead)
    zero_acc<<<2080, 256, 0, stream>>>((f4*)AccBuf, (f4*)AccL);
    // 5. split-K MFMA flash attention, 2 heads/block
    flash_attn_mfma<<<dim3(48, 16), 256, 0, stream>>>(QKVb, VTg, Ob, AccBuf, AccL);
    // 6. combine attention partials for qt >= 16
    normalize_o<<<512, 256, 0, stream>>>(AccBuf, AccL, Ob);
    // 7. output projection (fp32, overwrites d_out scratch)
    gemm64_f<<<dim3(D / 64, S / 64), 256, 0, stream>>>(Ob, WoT, out, S, D, D);
}